// Round 11
// baseline (262.731 us; speedup 1.0000x reference)
//
#include <hip/hip_runtime.h>
#include <hip/hip_bf16.h>

typedef unsigned short u16;
typedef unsigned int u32;
typedef u16 u16x8 __attribute__((ext_vector_type(8)));
typedef u16 u16x4 __attribute__((ext_vector_type(4)));
typedef __bf16 bf16x8 __attribute__((ext_vector_type(8)));
typedef float f32x4 __attribute__((ext_vector_type(4)));

#define B_SZ 2
#define T_SZ 2048
#define DMODEL 1024
#define DINNER 2048
#define DSTATE 128
#define NHEADS 32
#define HEADDIM 64
#define CONVDIM 2304
#define DINPROJ 4384
#define DINPROJ_P 4480        // padded to 35*128 for GEMM1 tiles
#define NROWS (B_SZ * T_SZ)   // 4096
#define L_CH 128
#define NCH 16                // chunks per batch (T/L)

__device__ __forceinline__ float bf2f(u16 u) {
    union { float f; u32 i; } v; v.i = ((u32)u) << 16; return v.f;
}
__device__ __forceinline__ u16 f2bf(float f) {
    union { float f; u32 i; } v; v.f = f;
    u32 r = v.i + 0x7FFFu + ((v.i >> 16) & 1u);
    return (u16)(r >> 16);
}
__device__ __forceinline__ bf16x8 ldfrag(const u16* p) {
    return __builtin_bit_cast(bf16x8, *(const u16x8*)p);
}
__device__ __forceinline__ void gload_lds16(const u16* g, u16* l) {
    __builtin_amdgcn_global_load_lds(
        (const __attribute__((address_space(1))) unsigned int*)g,
        (__attribute__((address_space(3))) unsigned int*)l, 16, 0, 0);
}

// ---------------- fused prologue: trans(W_in) | trans(W_out) | rmsnorm(x) | cwprep ----------------
__device__ void trans_tile(const float* __restrict__ in, u16* __restrict__ out,
                           int K, int N, int n0, int k0)
{
    __shared__ u16 tile[64][72];
    const int tid = threadIdx.x;
#pragma unroll
    for (int r = 0; r < 4; r++) {
        int idx = r * 256 + tid;           // 1024 float4 slots = 64k x 16n4
        int k = idx >> 4, n4 = (idx & 15) << 2;
        const float* src = &in[(size_t)(k0 + k) * N + n0 + n4];
        float4 v;
        if (n0 + n4 + 3 < N) {
            v = *(const float4*)src;
        } else {
            v.x = (n0 + n4 + 0 < N) ? src[0] : 0.f;
            v.y = (n0 + n4 + 1 < N) ? src[1] : 0.f;
            v.z = (n0 + n4 + 2 < N) ? src[2] : 0.f;
            v.w = (n0 + n4 + 3 < N) ? src[3] : 0.f;
        }
        tile[n4 + 0][k] = f2bf(v.x);
        tile[n4 + 1][k] = f2bf(v.y);
        tile[n4 + 2][k] = f2bf(v.z);
        tile[n4 + 3][k] = f2bf(v.w);
    }
    __syncthreads();
#pragma unroll
    for (int r = 0; r < 2; r++) {
        int idx = r * 256 + tid;           // 512 vec8 slots = 64n x 8k8
        int n = idx >> 3, k8 = (idx & 7) << 3;
        u16x8 vv = *(const u16x8*)&tile[n][k8];
        *(u16x8*)&out[(size_t)(n0 + n) * K + k0 + k8] = vv;
    }
}

__global__ __launch_bounds__(256) void prep_kernel(
    const float* __restrict__ W_in, u16* __restrict__ W_inT,
    const float* __restrict__ W_out, u16* __restrict__ W_outT,
    const float* __restrict__ x, const float* __restrict__ nw, u16* __restrict__ xn,
    const float* __restrict__ cw, u16* __restrict__ cwT)
{
    const int blk = blockIdx.x;
    const int tid = threadIdx.x;
    if (blk < 1120) {
        trans_tile(W_in, W_inT, DMODEL, DINPROJ, (blk % 70) * 64, (blk / 70) * 64);
    } else if (blk < 1632) {
        int idx = blk - 1120;
        trans_tile(W_out, W_outT, DINNER, DMODEL, (idx % 16) * 64, (idx / 16) * 64);
    } else if (blk < 5728) {
        const int row = blk - 1632;
        float4 v = ((const float4*)(x + (size_t)row * DMODEL))[tid];
        float ss = v.x * v.x + v.y * v.y + v.z * v.z + v.w * v.w;
#pragma unroll
        for (int o = 32; o; o >>= 1) ss += __shfl_xor(ss, o);
        __shared__ float red[4];
        if ((tid & 63) == 0) red[tid >> 6] = ss;
        __syncthreads();
        ss = red[0] + red[1] + red[2] + red[3];
        float sc = rsqrtf(ss / (float)DMODEL + 1e-5f);
        float4 wv = ((const float4*)nw)[tid];
        u16x4 o4;
        o4[0] = f2bf(v.x * sc * wv.x);
        o4[1] = f2bf(v.y * sc * wv.y);
        o4[2] = f2bf(v.z * sc * wv.z);
        o4[3] = f2bf(v.w * sc * wv.w);
        *(u16x4*)&xn[(size_t)row * DMODEL + tid * 4] = o4;
    } else {
        for (int idx = tid; idx < 4 * CONVDIM; idx += 256) {
            int k = idx / CONVDIM, c = idx - k * CONVDIM;
            cwT[idx] = f2bf(cw[c * 4 + k]);
        }
    }
}

// ---------------- 128x128 bf16 MFMA GEMM, BK=64, XOR-swizzled, compile-time K -------------------
// GEMM1, grid 1120, r7-verified XCD-region remap (fetch 77.8->35.1MB).
// r11: swapped MFMA operands -> acc[mt][nt] = D[n][m]:
//   n = n0+wn+nt*16+quad*4+rg (4 consecutive per lane -> u16x4 store), m = m0+wm+mt*16+ml.
template<int KC>
__global__ __launch_bounds__(256) void gemm128_kernel(
    const u16* __restrict__ A, const u16* __restrict__ BT, u16* __restrict__ C,
    int Nst)
{
    __shared__ u16 As[128 * 64];
    __shared__ u16 Bs[128 * 64];
    const int tid = threadIdx.x;
    const int l = tid & 63, w = tid >> 6;
    const int bid = blockIdx.x;
    int s = (bid & 7) * 140 + (bid >> 3);      // XCD-contiguous index, [0,1120)
    int mc = s / 280, r2 = s - mc * 280;       // 4 m-chunks of 8 tiles
    int nc = (r2 >= 144) ? 1 : 0;
    int local = r2 - nc * 144;
    int nloc = local >> 3, mloc = local & 7;   // m-fast within region
    const int m0 = (mc * 8 + mloc) * 128;
    const int n0 = (nc * 18 + nloc) * 128;
    const int ml = l & 15, quad = l >> 4;
    const int wm = (w & 1) * 64, wn = (w >> 1) * 64;
    f32x4 acc[4][4] = {};
    const int srow = l >> 3;
    const int sgx = (l & 7) ^ srow;
    const u16* Ag = A + (size_t)(m0 + w * 8 + srow) * KC + sgx * 8;
    const u16* Bg = BT + (size_t)(n0 + w * 8 + srow) * KC + sgx * 8;
    u16* const As_w = &As[(w * 8) * 64];
    u16* const Bs_w = &Bs[(w * 8) * 64];

#pragma unroll 4
    for (int k0 = 0; k0 < KC; k0 += 64) {
        __syncthreads();
#pragma unroll
        for (int j = 0; j < 4; j++) {
            gload_lds16(Ag + (size_t)(j * 32) * KC + k0, As_w + j * 32 * 64);
            gload_lds16(Bg + (size_t)(j * 32) * KC + k0, Bs_w + j * 32 * 64);
        }
        __syncthreads();
#pragma unroll
        for (int ks4 = 0; ks4 < 2; ks4++) {
            bf16x8 af[4], bfr[4];
#pragma unroll
            for (int i = 0; i < 4; i++)
                af[i] = ldfrag(&As[(wm + i * 16 + ml) * 64 +
                                   (((ks4 * 4 + quad) ^ (ml & 7)) * 8)]);
#pragma unroll
            for (int i = 0; i < 4; i++)
                bfr[i] = ldfrag(&Bs[(wn + i * 16 + ml) * 64 +
                                    (((ks4 * 4 + quad) ^ (ml & 7)) * 8)]);
#pragma unroll
            for (int mt = 0; mt < 4; mt++)
#pragma unroll
                for (int nt = 0; nt < 4; nt++)
                    acc[mt][nt] = __builtin_amdgcn_mfma_f32_16x16x32_bf16(
                        bfr[nt], af[mt], acc[mt][nt], 0, 0, 0);
        }
    }
    // swapped-layout epilogue: u16x4 stores (16 vs 64 scalar); 4384 % 4 == 0 ->
    // whole-vector guard exact for padded cols
#pragma unroll
    for (int mt = 0; mt < 4; mt++) {
        const int m = m0 + wm + mt * 16 + ml;
#pragma unroll
        for (int nt = 0; nt < 4; nt++) {
            const int nb = n0 + wn + nt * 16 + quad * 4;
            if (nb < Nst) {
                u16x4 pk;
#pragma unroll
                for (int rg = 0; rg < 4; rg++) pk[rg] = f2bf(acc[mt][nt][rg]);
                *(u16x4*)&C[(size_t)m * Nst + nb] = pk;
            }
        }
    }
}

// ---------------- 128(M)x64(N) bf16 GEMM + residual, float out (GEMM2), XCD-region grid --------
template<int KC>
__global__ __launch_bounds__(256) void gemm128x64_kernel(
    const u16* __restrict__ A, const u16* __restrict__ BT, float* __restrict__ C,
    const float* __restrict__ Res, int Nst)
{
    __shared__ u16 As[128 * 64];
    __shared__ u16 Bs[64 * 64];
    const int tid = threadIdx.x;
    const int l = tid & 63, w = tid >> 6;
    const int bid = blockIdx.x;
    const int xcd = bid & 7, local = bid >> 3;     // 64 blocks per XCD
    const int mc = xcd >> 1, nc = xcd & 1;
    const int nloc = local & 7, mloc = local >> 3; // n-fast within region
    const int m0 = (mc * 8 + mloc) * 128;
    const int n0 = (nc * 8 + nloc) * 64;
    const int ml = l & 15, quad = l >> 4;
    const int wm = w * 32;
    f32x4 acc[2][4] = {};
    const int srow = l >> 3;
    const int sgx = (l & 7) ^ srow;
    const u16* Ag = A + (size_t)(m0 + w * 8 + srow) * KC + sgx * 8;
    const u16* Bg = BT + (size_t)(n0 + w * 8 + srow) * KC + sgx * 8;
    u16* const As_w = &As[(w * 8) * 64];
    u16* const Bs_w = &Bs[(w * 8) * 64];

#pragma unroll 4
    for (int k0 = 0; k0 < KC; k0 += 64) {
        __syncthreads();
#pragma unroll
        for (int j = 0; j < 4; j++)
            gload_lds16(Ag + (size_t)(j * 32) * KC + k0, As_w + j * 32 * 64);
#pragma unroll
        for (int j = 0; j < 2; j++)
            gload_lds16(Bg + (size_t)(j * 32) * KC + k0, Bs_w + j * 32 * 64);
        __syncthreads();
#pragma unroll
        for (int ks4 = 0; ks4 < 2; ks4++) {
            bf16x8 af[2], bfr[4];
#pragma unroll
            for (int i = 0; i < 2; i++)
                af[i] = ldfrag(&As[(wm + i * 16 + ml) * 64 +
                                   (((ks4 * 4 + quad) ^ (ml & 7)) * 8)]);
#pragma unroll
            for (int i = 0; i < 4; i++)
                bfr[i] = ldfrag(&Bs[(i * 16 + ml) * 64 +
                                    (((ks4 * 4 + quad) ^ (ml & 7)) * 8)]);
#pragma unroll
            for (int mt = 0; mt < 2; mt++)
#pragma unroll
                for (int nt = 0; nt < 4; nt++)
                    acc[mt][nt] = __builtin_amdgcn_mfma_f32_16x16x32_bf16(
                        bfr[nt], af[mt], acc[mt][nt], 0, 0, 0);
        }
    }
    // swapped layout: m = m0+wm+mt*16+ml, n = n0+nt*16+quad*4+rg -> float4 + Res
#pragma unroll
    for (int mt = 0; mt < 2; mt++) {
        const int m = m0 + wm + mt * 16 + ml;
#pragma unroll
        for (int nt = 0; nt < 4; nt++) {
            const int nb = n0 + nt * 16 + quad * 4;
            float4 r = *(const float4*)&Res[(size_t)m * Nst + nb];
            float4 o;
            o.x = acc[mt][nt][0] + r.x;
            o.y = acc[mt][nt][1] + r.y;
            o.z = acc[mt][nt][2] + r.z;
            o.w = acc[mt][nt][3] + r.w;
            *(float4*)&C[(size_t)m * Nst + nb] = o;
        }
    }
}

// ---------------- depthwise causal conv(4) + bias + SiLU, 4-t x 8-ch per thread ----------------
#define NGRAN (CONVDIM / 8)   // 288 granules of 8 channels per row
__global__ __launch_bounds__(256) void conv_silu_kernel(
    const u16* __restrict__ zx, const u16* __restrict__ cwT,
    const float* __restrict__ cb, const float* __restrict__ dt_bias,
    u16* __restrict__ out, float* __restrict__ dts)
{
    int idx = blockIdx.x * 256 + threadIdx.x;   // over (NROWS/4)*NGRAN = 294912
    if (idx < B_SZ * NHEADS * T_SZ) {           // fused softplus(dt)
        int t = idx & (T_SZ - 1);
        int bh = idx >> 11;
        int h = bh & 31, b = bh >> 5;
        float v = bf2f(zx[(size_t)(b * T_SZ + t) * DINPROJ + (DINNER + CONVDIM) + h]) + dt_bias[h];
        float sp = (v > 20.f) ? v : log1pf(expf(v));
        dts[((size_t)bh << 11) + t] = sp;
    }
    int gr = idx % NGRAN;
    int q  = idx / NGRAN;            // [0, NROWS/4)
    int bt0 = q * 4;
    int t0 = bt0 & (T_SZ - 1);
    int c0 = gr * 8;
    const u16* base = zx + (size_t)bt0 * DINPROJ + DINNER + c0;
    u16x8 xr[7];
#pragma unroll
    for (int i = 0; i < 7; i++) {
        int tt = t0 + i - 3;
        if (tt < 0) xr[i] = u16x8{};
        else xr[i] = *(const u16x8*)(base + (ptrdiff_t)(i - 3) * DINPROJ);
    }
    u16x8 wv[4];
#pragma unroll
    for (int k = 0; k < 4; k++) wv[k] = *(const u16x8*)&cwT[k * CONVDIM + c0];
    float bias[8];
#pragma unroll
    for (int u = 0; u < 8; u++) bias[u] = cb[c0 + u];
#pragma unroll
    for (int u4 = 0; u4 < 4; u4++) {
        float acc[8];
#pragma unroll
        for (int u = 0; u < 8; u++) acc[u] = bias[u];
#pragma unroll
        for (int k = 0; k < 4; k++) {
            u16x8 xv = xr[u4 + k];
#pragma unroll
            for (int u = 0; u < 8; u++)
                acc[u] += bf2f(xv[u]) * bf2f(wv[k][u]);
        }
        u16 res[8];
#pragma unroll
        for (int u = 0; u < 8; u++) {
            float s = acc[u] / (1.f + expf(-acc[u]));
            res[u] = f2bf(s);
        }
        *(u16x8*)&out[(size_t)(bt0 + u4) * CONVDIM + c0] = *(u16x8*)res;
    }
}

// ---------------- K1: per-chunk cumsum (shfl-scan) + chunk-local state S = Xw^T @ B ------------
// T14 reorder: all 12 X/B global loads issued BEFORE the scan; BsT written
// immediately; X regs held across scan (HBM latency hides under scan barriers).
__global__ __launch_bounds__(256) void chunk_state_kernel(
    const u16* __restrict__ xbc, const float* __restrict__ dts_g,
    const float* __restrict__ A_log, float* __restrict__ cs_g, u16* __restrict__ S_bf)
{
    const int g = blockIdx.x;
    const int b = g >> 9, rem = g & 511, c = rem >> 5, h = rem & 31;
    const int tid = threadIdx.x;
    __shared__ float tmp[128], dt_l[128], d2e[128];
    __shared__ float wtot;
    __shared__ u16 Xw[64][136];
    __shared__ u16 BsT[128][136];
    const float A = -__expf(A_log[h]);
    const size_t rowbase = ((size_t)(b * T_SZ + c * L_CH)) * CONVDIM;
    // issue dt load first (scan critical path), then all X/B loads
    float dval = 0.f;
    if (tid < 128)
        dval = dts_g[(((size_t)(b * 32 + h)) << 11) + (c << 7) + tid];
    u16x8 xvr[4];
#pragma unroll
    for (int r = 0; r < 4; r++) {
        int vv = tid + r * 256;
        int t = vv >> 3, p0 = (vv & 7) << 3;
        xvr[r] = *(const u16x8*)&xbc[rowbase + (size_t)t * CONVDIM + h * 64 + p0];
    }
    // B rows: load + write LDS immediately (independent of scan)
#pragma unroll
    for (int r = 0; r < 8; r++) {
        int vv = tid + r * 256;
        int t = vv >> 4, n0 = (vv & 15) << 3;
        u16x8 bv = *(const u16x8*)&xbc[rowbase + (size_t)t * CONVDIM + DINNER + n0];
        const int tc = (t & 7) | (((t >> 3) ^ ((n0 >> 3) & 15)) << 3);
#pragma unroll
        for (int u = 0; u < 8; u++) BsT[n0 + u][tc] = bv[u];
    }
    // scan (2 barriers) overlaps the outstanding memory traffic
    float v = 0.f;
    if (tid < 128) {
        dt_l[tid] = dval;
        v = dval * A;
#pragma unroll
        for (int off = 1; off < 64; off <<= 1) {
            float pv = __shfl_up(v, off, 64);
            if ((tid & 63) >= off) v += pv;
        }
        if (tid == 63) wtot = v;
    }
    __syncthreads();
    if (tid < 128) {
        if (tid >= 64) v += wtot;
        tmp[tid] = v;
        cs_g[(((size_t)(b * 32 + h)) << 11) + (c << 7) + tid] = v;
    }
    __syncthreads();
    if (tid < 128) {
        d2e[tid] = __expf(tmp[127] - v) * dt_l[tid];
    }
    __syncthreads();
#pragma unroll
    for (int r = 0; r < 4; r++) {
        int vv = tid + r * 256;
        int t = vv >> 3, p0 = (vv & 7) << 3;
        float s = d2e[t];
        const int tc = (t & 7) | (((t >> 3) ^ ((p0 >> 3) & 15)) << 3);
#pragma unroll
        for (int u = 0; u < 8; u++) Xw[p0 + u][tc] = f2bf(bf2f(xvr[r][u]) * s);
    }
    __syncthreads();
    const int lane = tid & 63, wv = tid >> 6, ml = lane & 15, quad = lane >> 4;
    f32x4 acc[8] = {};
    const int arow = wv * 16 + ml;
    const int asw = (arow >> 3) & 15;
    for (int k0 = 0; k0 < 128; k0 += 32) {
        bf16x8 af = ldfrag(&Xw[arow][(((k0 >> 3) + quad) ^ asw) << 3]);
#pragma unroll
        for (int nt = 0; nt < 8; nt++) {
            const int brow = nt * 16 + ml;
            bf16x8 bf = ldfrag(&BsT[brow][(((k0 >> 3) + quad) ^ ((brow >> 3) & 15)) << 3]);
            acc[nt] = __builtin_amdgcn_mfma_f32_16x16x32_bf16(bf, af, acc[nt], 0, 0, 0);
        }
    }
    // swapped layout: p = wv*16+ml, n = nt*16+quad*4+rg -> u16x4 stores
    const size_t base = (size_t)g * 8192;
    const int p = wv * 16 + ml;
#pragma unroll
    for (int nt = 0; nt < 8; nt++) {
        const int nb = nt * 16 + quad * 4;
        u16x4 pk;
#pragma unroll
        for (int rg = 0; rg < 4; rg++) pk[rg] = f2bf(acc[nt][rg]);
        *(u16x4*)&S_bf[base + p * 128 + nb] = pk;
    }
}

// ---------------- K2: inter-chunk recurrence, in-place, element-parallel, load-pipelined --------
__global__ __launch_bounds__(256) void state_pass_kernel(
    const float* __restrict__ cs_g, u16* __restrict__ S_bf)
{
    const int bh = blockIdx.x >> 3, b = bh >> 5, h = bh & 31;
    const int off = (blockIdx.x & 7) * 1024 + threadIdx.x * 4;
    const float* csb = cs_g + (((size_t)(b * 32 + h)) << 11);
    float H[4] = {0.f, 0.f, 0.f, 0.f};
    const size_t step = (size_t)32 * 8192;
    size_t slot = ((size_t)(b * NCH * 32 + h)) * 8192 + off;
    u16x4 tv = *(const u16x4*)&S_bf[slot];
    for (int c = 0; c < NCH; c++) {
        u16x4 tvn = tv;
        if (c + 1 < NCH) tvn = *(const u16x4*)&S_bf[slot + step];   // prefetch next
        float decay = __expf(csb[(c << 7) + 127]);
        u16x4 hw;
#pragma unroll
        for (int i = 0; i < 4; i++) hw[i] = f2bf(H[i]);
        *(u16x4*)&S_bf[slot] = hw;                                   // store prev-state
#pragma unroll
        for (int i = 0; i < 4; i++) H[i] = H[i] * decay + bf2f(tv[i]);
        tv = tvn; slot += step;
    }
}

// ---------------- K3: chunk output -- LDS-staged B/H + swapped D[p][t] accumulators ------------
__global__ __launch_bounds__(256) void chunk_out_kernel(
    const u16* __restrict__ xbc, const float* __restrict__ dts_g,
    const float* __restrict__ cs_g, const u16* __restrict__ H_bf,
    const float* __restrict__ Dv, u16* __restrict__ yraw)
{
    const int g = blockIdx.x;
    const int b = g >> 9, rem = g & 511, c = rem >> 5, h = rem & 31;
    const int tid = threadIdx.x;
    __shared__ u16 Xs[64][136];     // X^T [p][t], granule-XOR swizzled
    __shared__ u16 Gs[128][40];     // masked P tile
    __shared__ u16 Hs[64 * 128];    // H [p][n], row-granule swizzled
    __shared__ u16 Bsh[128 * 128];  // B [j][n], row-granule swizzled
    __shared__ float cs_l[128], P_l[128], dt_l[128];
    const size_t rowbase = ((size_t)(b * T_SZ + c * L_CH)) * CONVDIM;
    const u16* Cg = xbc + rowbase + DINNER + 128;
    const u16* Bg = xbc + rowbase + DINNER;
    const u16* Hg = H_bf + (size_t)g * 8192;
    // async coalesced staging of H (16KB) and B (32KB); granule pre-swizzle on source
#pragma unroll
    for (int r = 0; r < 4; r++) {
        int i = r * 256 + tid;
        int row = i >> 4, slot = i & 15;
        gload_lds16(Hg + row * 128 + ((slot ^ (row & 15)) << 3), &Hs[i * 8]);
    }
#pragma unroll
    for (int r = 0; r < 8; r++) {
        int i = r * 256 + tid;
        int row = i >> 4, slot = i & 15;
        gload_lds16(Bg + (size_t)row * CONVDIM + ((slot ^ (row & 15)) << 3), &Bsh[i * 8]);
    }
    if (tid < 128) {
        float cs = cs_g[(((size_t)(b * 32 + h)) << 11) + (c << 7) + tid];
        cs_l[tid] = cs; P_l[tid] = __expf(cs);
        dt_l[tid] = dts_g[(((size_t)(b * 32 + h)) << 11) + (c << 7) + tid];
    }
#pragma unroll
    for (int r = 0; r < 4; r++) {
        int v = tid + r * 256; int t = v >> 3, p0 = (v & 7) << 3;
        u16x8 xv = *(const u16x8*)&xbc[rowbase + (size_t)t * CONVDIM + h * 64 + p0];
        const int tc = (t & 7) | (((t >> 3) ^ ((p0 >> 3) & 15)) << 3);
#pragma unroll
        for (int u = 0; u < 8; u++) Xs[p0 + u][tc] = xv[u];
    }
    __syncthreads();
    const int lane = tid & 63, wv = tid >> 6, ml = lane & 15, quad = lane >> 4;
    const int trow = wv * 32;
    // HOIST: C fragments (t-rows of this wave), 2nd operand everywhere.
    bf16x8 cf[2][4];
#pragma unroll
    for (int mt = 0; mt < 2; mt++)
#pragma unroll
        for (int kk = 0; kk < 4; kk++)
            cf[mt][kk] = ldfrag(Cg + (size_t)(trow + mt * 16 + ml) * CONVDIM + kk * 32 + quad * 8);
    // Y = C.H^T, swapped: accY[mt][pt] = D[p][t], p = pt*16+quad*4+rg, t = trow+mt*16+ml
    f32x4 accY[2][4] = {};
#pragma unroll
    for (int kk = 0; kk < 4; kk++) {
        const int sw = (((kk << 2) + quad) ^ ml) << 3;   // row&15 == ml
#pragma unroll
        for (int pt = 0; pt < 4; pt++) {
            bf16x8 bf = ldfrag(&Hs[(pt * 16 + ml) * 128 + sw]);
            accY[0][pt] = __builtin_amdgcn_mfma_f32_16x16x32_bf16(bf, cf[0][kk], accY[0][pt], 0, 0, 0);
            accY[1][pt] = __builtin_amdgcn_mfma_f32_16x16x32_bf16(bf, cf[1][kk], accY[1][pt], 0, 0, 0);
        }
    }
#pragma unroll
    for (int mt = 0; mt < 2; mt++) {
        const float pp = P_l[trow + mt * 16 + ml];
#pragma unroll
        for (int pt = 0; pt < 4; pt++)
#pragma unroll
            for (int rg = 0; rg < 4; rg++) accY[mt][pt][rg] *= pp;
    }
    for (int js = 0; js < 4; js++) {
        const int j0 = js * 32;
        // Ga[mt][jt] = D[j][t]: j = j0+jt*16+quad*4+rg, t = trow+mt*16+ml
        f32x4 Ga[2][2] = {};
#pragma unroll
        for (int kk = 0; kk < 4; kk++) {
            const int sw = (((kk << 2) + quad) ^ ml) << 3;   // row&15 == ml
            bf16x8 bf0 = ldfrag(&Bsh[(j0 + ml) * 128 + sw]);
            bf16x8 bf1 = ldfrag(&Bsh[(j0 + 16 + ml) * 128 + sw]);
            Ga[0][0] = __builtin_amdgcn_mfma_f32_16x16x32_bf16(bf0, cf[0][kk], Ga[0][0], 0, 0, 0);
            Ga[0][1] = __builtin_amdgcn_mfma_f32_16x16x32_bf16(bf1, cf[0][kk], Ga[0][1], 0, 0, 0);
            Ga[1][0] = __builtin_amdgcn_mfma_f32_16x16x32_bf16(bf0, cf[1][kk], Ga[1][0], 0, 0, 0);
            Ga[1][1] = __builtin_amdgcn_mfma_f32_16x16x32_bf16(bf1, cf[1][kk], Ga[1][1], 0, 0, 0);
        }
        // causal mask * decay -> Gs (u16x4 writes: 4 consecutive j at fixed t)
#pragma unroll
        for (int mt = 0; mt < 2; mt++) {
            const int t = trow + mt * 16 + ml;
            const float cst = cs_l[t];
#pragma unroll
            for (int jt = 0; jt < 2; jt++) {
                u16x4 pk;
#pragma unroll
                for (int rg = 0; rg < 4; rg++) {
                    int j = j0 + jt * 16 + quad * 4 + rg;
                    float val = 0.f;
                    if (t >= j) val = Ga[mt][jt][rg] * __expf(cst - cs_l[j]) * dt_l[j];
                    pk[rg] = f2bf(val);
                }
                *(u16x4*)&Gs[t][jt * 16 + quad * 4] = pk;
            }
        }
#pragma unroll
        for (int mt = 0; mt < 2; mt++) {
            bf16x8 ag = ldfrag(&Gs[trow + mt * 16 + ml][quad * 8]);
#pragma unroll
            for (int pt = 0; pt < 4; pt++) {
                const int xrow = pt * 16 + ml;
                bf16x8 bx = ldfrag(&Xs[xrow][(((j0 >> 3) + quad) ^ ((xrow >> 3) & 15)) << 3]);
                accY[mt][pt] = __builtin_amdgcn_mfma_f32_16x16x32_bf16(bx, ag, accY[mt][pt], 0, 0, 0);
            }
        }
    }
    const float Dh = Dv[h];
    const size_t ybase = ((size_t)(b * T_SZ + c * L_CH)) * DINNER;
#pragma unroll
    for (int mt = 0; mt < 2; mt++) {
        const int t = trow + mt * 16 + ml;
#pragma unroll
        for (int pt = 0; pt < 4; pt++) {
            const int pb = pt * 16 + quad * 4;
            const int tc = (t & 7) | (((t >> 3) ^ ((pb >> 3) & 15)) << 3);
            u16x4 pk;
#pragma unroll
            for (int rg = 0; rg < 4; rg++)
                pk[rg] = f2bf(accY[mt][pt][rg] + Dh * bf2f(Xs[pb + rg][tc]));
            *(u16x4*)&yraw[ybase + (size_t)t * DINNER + h * 64 + pb] = pk;
        }
    }
}

// ---------------- y = rmsnorm(yraw * silu(z)) * gnorm_w (D=2048), vectorized ----------------
__global__ __launch_bounds__(256) void postnorm_kernel(
    const u16* __restrict__ yraw, const u16* __restrict__ zx,
    const float* __restrict__ gw, u16* __restrict__ out)
{
    const int row = blockIdx.x;
    const int tid = threadIdx.x;
    u16x8 yv = *(const u16x8*)(yraw + (size_t)row * DINNER + tid * 8);
    u16x8 zv = *(const u16x8*)(zx + (size_t)row * DINPROJ + tid * 8);
    float vals[8]; float ss = 0.f;
#pragma unroll
    for (int i = 0; i < 8; i++) {
        float y = bf2f(yv[i]);
        float z = bf2f(zv[i]);
        float s = z / (1.f + expf(-z));
        float t = y * s; vals[i] = t; ss += t * t;
    }
#pragma unroll
    for (int o = 32; o; o >>= 1) ss += __shfl_xor(ss, o);
    __shared__ float red[4];
    if ((tid & 63) == 0) red[tid >> 6] = ss;
    __syncthreads();
    ss = red[0] + red[1] + red[2] + red[3];
    float sc = rsqrtf(ss / (float)DINNER + 1e-5f);
    u16 o8[8];
#pragma unroll
    for (int i = 0; i < 8; i++) o8[i] = f2bf(vals[i] * sc * gw[tid * 8 + i]);
    *(u16x8*)(out + (size_t)row * DINNER + tid * 8) = *(u16x8*)o8;
}

extern "C" void kernel_launch(void* const* d_in, const int* in_sizes, int n_in,
                              void* d_out, int out_size, void* d_ws, size_t ws_size,
                              hipStream_t stream) {
    const float* x       = (const float*)d_in[0];
    const float* W_in    = (const float*)d_in[1];
    const float* conv_w  = (const float*)d_in[2];
    const float* conv_b  = (const float*)d_in[3];
    const float* dt_bias = (const float*)d_in[4];
    const float* A_log   = (const float*)d_in[5];
    const float* Dv      = (const float*)d_in[6];
    const float* norm_w  = (const float*)d_in[7];
    const float* gnorm_w = (const float*)d_in[8];
    const float* W_out   = (const float*)d_in[9];
    float* out = (float*)d_out;

    char* ws = (char*)d_ws;
    u16*   xn    = (u16*)(ws);                  // [0, 8.39M)  (aliases S_bf later)
    u16*   W_inT = (u16*)(ws + 8388608);        // [4480][1024] bf16 (dead after GEMM1)
    u16*   S_bf  = (u16*)(ws);                  // 16.78M, from chunk_state on
    float* cs_g  = (float*)(ws + 16777216);
    u16*   zx    = (u16*)(ws + 17563648);       // 35,913,728 B
    u16*   xbc   = (u16*)(ws + 53477376);       // 18,874,368 B
    float* dts   = (float*)(ws + 72351744);     //    524,288 B
    u16*   yraw  = (u16*)(ws + 72876032);       // 16,777,216 B
    u16*   cwT   = (u16*)(ws + 89653248);       //     18,432 B
    u16*   W_outT= (u16*)(ws + 89671680);       //  4,194,304 B (end 93,865,984)
    u16*   ynorm = yraw;                        // postnorm in-place safe

    prep_kernel<<<5729, 256, 0, stream>>>(
        W_in, W_inT, W_out, W_outT, x, norm_w, xn, conv_w, cwT);
    // GEMM1: single 1120-block launch, r7 XCD-region swizzle + u16x4 epilogue
    gemm128_kernel<DMODEL><<<1120, 256, 0, stream>>>(
        xn, W_inT, zx, DINPROJ);
    conv_silu_kernel<<<(NROWS / 4 * NGRAN) / 256, 256, 0, stream>>>(
        zx, cwT, conv_b, dt_bias, xbc, dts);
    chunk_state_kernel<<<B_SZ * NCH * NHEADS, 256, 0, stream>>>(xbc, dts, A_log, cs_g, S_bf);
    state_pass_kernel<<<B_SZ * NHEADS * 8, 256, 0, stream>>>(cs_g, S_bf);
    chunk_out_kernel<<<B_SZ * NCH * NHEADS, 256, 0, stream>>>(xbc, dts, cs_g, S_bf, Dv, yraw);
    postnorm_kernel<<<NROWS, 256, 0, stream>>>(yraw, zx, gnorm_w, ynorm);
    // GEMM2: 128x64, 1D grid 512 with XCD-region mapping (64 blocks/XCD, n-fast)
    gemm128x64_kernel<DINNER><<<512, 256, 0, stream>>>(
        ynorm, W_outT, out, x, DMODEL);
}

// Round 12
// 248.870 us; speedup vs baseline: 1.0557x; 1.0557x over previous
//
#include <hip/hip_runtime.h>
#include <hip/hip_bf16.h>

typedef unsigned short u16;
typedef unsigned int u32;
typedef u16 u16x8 __attribute__((ext_vector_type(8)));
typedef u16 u16x4 __attribute__((ext_vector_type(4)));
typedef __bf16 bf16x8 __attribute__((ext_vector_type(8)));
typedef float f32x4 __attribute__((ext_vector_type(4)));

#define B_SZ 2
#define T_SZ 2048
#define DMODEL 1024
#define DINNER 2048
#define DSTATE 128
#define NHEADS 32
#define HEADDIM 64
#define CONVDIM 2304
#define DINPROJ 4384
#define DINPROJ_P 4480        // padded to 35*128 for GEMM1 tiles
#define NROWS (B_SZ * T_SZ)   // 4096
#define L_CH 128
#define NCH 16                // chunks per batch (T/L)

__device__ __forceinline__ float bf2f(u16 u) {
    union { float f; u32 i; } v; v.i = ((u32)u) << 16; return v.f;
}
__device__ __forceinline__ u16 f2bf(float f) {
    union { float f; u32 i; } v; v.f = f;
    u32 r = v.i + 0x7FFFu + ((v.i >> 16) & 1u);
    return (u16)(r >> 16);
}
__device__ __forceinline__ bf16x8 ldfrag(const u16* p) {
    return __builtin_bit_cast(bf16x8, *(const u16x8*)p);
}
__device__ __forceinline__ void gload_lds16(const u16* g, u16* l) {
    __builtin_amdgcn_global_load_lds(
        (const __attribute__((address_space(1))) unsigned int*)g,
        (__attribute__((address_space(3))) unsigned int*)l, 16, 0, 0);
}

// ---------------- fused prologue: trans(W_in) | trans(W_out) | rmsnorm(x) | cwprep ----------------
__device__ void trans_tile(const float* __restrict__ in, u16* __restrict__ out,
                           int K, int N, int n0, int k0)
{
    __shared__ u16 tile[64][72];
    const int tid = threadIdx.x;
#pragma unroll
    for (int r = 0; r < 4; r++) {
        int idx = r * 256 + tid;           // 1024 float4 slots = 64k x 16n4
        int k = idx >> 4, n4 = (idx & 15) << 2;
        const float* src = &in[(size_t)(k0 + k) * N + n0 + n4];
        float4 v;
        if (n0 + n4 + 3 < N) {
            v = *(const float4*)src;
        } else {
            v.x = (n0 + n4 + 0 < N) ? src[0] : 0.f;
            v.y = (n0 + n4 + 1 < N) ? src[1] : 0.f;
            v.z = (n0 + n4 + 2 < N) ? src[2] : 0.f;
            v.w = (n0 + n4 + 3 < N) ? src[3] : 0.f;
        }
        tile[n4 + 0][k] = f2bf(v.x);
        tile[n4 + 1][k] = f2bf(v.y);
        tile[n4 + 2][k] = f2bf(v.z);
        tile[n4 + 3][k] = f2bf(v.w);
    }
    __syncthreads();
#pragma unroll
    for (int r = 0; r < 2; r++) {
        int idx = r * 256 + tid;           // 512 vec8 slots = 64n x 8k8
        int n = idx >> 3, k8 = (idx & 7) << 3;
        u16x8 vv = *(const u16x8*)&tile[n][k8];
        *(u16x8*)&out[(size_t)(n0 + n) * K + k0 + k8] = vv;
    }
}

__global__ __launch_bounds__(256) void prep_kernel(
    const float* __restrict__ W_in, u16* __restrict__ W_inT,
    const float* __restrict__ W_out, u16* __restrict__ W_outT,
    const float* __restrict__ x, const float* __restrict__ nw, u16* __restrict__ xn,
    const float* __restrict__ cw, u16* __restrict__ cwT)
{
    const int blk = blockIdx.x;
    const int tid = threadIdx.x;
    if (blk < 1120) {
        trans_tile(W_in, W_inT, DMODEL, DINPROJ, (blk % 70) * 64, (blk / 70) * 64);
    } else if (blk < 1632) {
        int idx = blk - 1120;
        trans_tile(W_out, W_outT, DINNER, DMODEL, (idx % 16) * 64, (idx / 16) * 64);
    } else if (blk < 5728) {
        const int row = blk - 1632;
        float4 v = ((const float4*)(x + (size_t)row * DMODEL))[tid];
        float ss = v.x * v.x + v.y * v.y + v.z * v.z + v.w * v.w;
#pragma unroll
        for (int o = 32; o; o >>= 1) ss += __shfl_xor(ss, o);
        __shared__ float red[4];
        if ((tid & 63) == 0) red[tid >> 6] = ss;
        __syncthreads();
        ss = red[0] + red[1] + red[2] + red[3];
        float sc = rsqrtf(ss / (float)DMODEL + 1e-5f);
        float4 wv = ((const float4*)nw)[tid];
        u16x4 o4;
        o4[0] = f2bf(v.x * sc * wv.x);
        o4[1] = f2bf(v.y * sc * wv.y);
        o4[2] = f2bf(v.z * sc * wv.z);
        o4[3] = f2bf(v.w * sc * wv.w);
        *(u16x4*)&xn[(size_t)row * DMODEL + tid * 4] = o4;
    } else {
        for (int idx = tid; idx < 4 * CONVDIM; idx += 256) {
            int k = idx / CONVDIM, c = idx - k * CONVDIM;
            cwT[idx] = f2bf(cw[c * 4 + k]);
        }
    }
}

// ---------------- 128x128 bf16 MFMA GEMM, BK=64, XOR-swizzled, compile-time K (r8-exact) --------
// Grid 1120, r7-verified XCD-region remap (fetch 77.8->35.1MB, 44.8us @ healthy clock).
// r11 ERRATA: swapped u16x4 epilogue REGRESSED here (FETCH +7.6MB: 16-row-scatter
// stores thrash per-XCD L2 write-allocate). Scalar 4-row epilogue restored.
template<int KC>
__global__ __launch_bounds__(256) void gemm128_kernel(
    const u16* __restrict__ A, const u16* __restrict__ BT, u16* __restrict__ C,
    int Nst)
{
    __shared__ u16 As[128 * 64];
    __shared__ u16 Bs[128 * 64];
    const int tid = threadIdx.x;
    const int l = tid & 63, w = tid >> 6;
    const int bid = blockIdx.x;
    int s = (bid & 7) * 140 + (bid >> 3);      // XCD-contiguous index, [0,1120)
    int mc = s / 280, r2 = s - mc * 280;       // 4 m-chunks of 8 tiles
    int nc = (r2 >= 144) ? 1 : 0;
    int local = r2 - nc * 144;
    int nloc = local >> 3, mloc = local & 7;   // m-fast within region
    const int m0 = (mc * 8 + mloc) * 128;
    const int n0 = (nc * 18 + nloc) * 128;
    const int ml = l & 15, quad = l >> 4;
    const int wm = (w & 1) * 64, wn = (w >> 1) * 64;
    f32x4 acc[4][4] = {};
    const int srow = l >> 3;
    const int sgx = (l & 7) ^ srow;
    const u16* Ag = A + (size_t)(m0 + w * 8 + srow) * KC + sgx * 8;
    const u16* Bg = BT + (size_t)(n0 + w * 8 + srow) * KC + sgx * 8;
    u16* const As_w = &As[(w * 8) * 64];
    u16* const Bs_w = &Bs[(w * 8) * 64];

#pragma unroll 4
    for (int k0 = 0; k0 < KC; k0 += 64) {
        __syncthreads();
#pragma unroll
        for (int j = 0; j < 4; j++) {
            gload_lds16(Ag + (size_t)(j * 32) * KC + k0, As_w + j * 32 * 64);
            gload_lds16(Bg + (size_t)(j * 32) * KC + k0, Bs_w + j * 32 * 64);
        }
        __syncthreads();
#pragma unroll
        for (int ks4 = 0; ks4 < 2; ks4++) {
            bf16x8 af[4], bfr[4];
#pragma unroll
            for (int i = 0; i < 4; i++)
                af[i] = ldfrag(&As[(wm + i * 16 + ml) * 64 +
                                   (((ks4 * 4 + quad) ^ (ml & 7)) * 8)]);
#pragma unroll
            for (int i = 0; i < 4; i++)
                bfr[i] = ldfrag(&Bs[(wn + i * 16 + ml) * 64 +
                                    (((ks4 * 4 + quad) ^ (ml & 7)) * 8)]);
#pragma unroll
            for (int mt = 0; mt < 4; mt++)
#pragma unroll
                for (int nt = 0; nt < 4; nt++)
                    acc[mt][nt] = __builtin_amdgcn_mfma_f32_16x16x32_bf16(
                        af[mt], bfr[nt], acc[mt][nt], 0, 0, 0);
        }
    }
#pragma unroll
    for (int mt = 0; mt < 4; mt++)
#pragma unroll
        for (int nt = 0; nt < 4; nt++)
#pragma unroll
            for (int rg = 0; rg < 4; rg++) {
                int m = m0 + wm + mt * 16 + quad * 4 + rg;
                int n = n0 + wn + nt * 16 + ml;
                if (n < Nst)
                    C[(size_t)m * Nst + n] = f2bf(acc[mt][nt][rg]);
            }
}

// ---------------- 128(M)x64(N) bf16 GEMM + residual, float out (GEMM2), XCD-region grid --------
template<int KC>
__global__ __launch_bounds__(256) void gemm128x64_kernel(
    const u16* __restrict__ A, const u16* __restrict__ BT, float* __restrict__ C,
    const float* __restrict__ Res, int Nst)
{
    __shared__ u16 As[128 * 64];
    __shared__ u16 Bs[64 * 64];
    const int tid = threadIdx.x;
    const int l = tid & 63, w = tid >> 6;
    const int bid = blockIdx.x;
    const int xcd = bid & 7, local = bid >> 3;     // 64 blocks per XCD
    const int mc = xcd >> 1, nc = xcd & 1;
    const int nloc = local & 7, mloc = local >> 3; // n-fast within region
    const int m0 = (mc * 8 + mloc) * 128;
    const int n0 = (nc * 8 + nloc) * 64;
    const int ml = l & 15, quad = l >> 4;
    const int wm = w * 32;
    f32x4 acc[2][4] = {};
    const int srow = l >> 3;
    const int sgx = (l & 7) ^ srow;
    const u16* Ag = A + (size_t)(m0 + w * 8 + srow) * KC + sgx * 8;
    const u16* Bg = BT + (size_t)(n0 + w * 8 + srow) * KC + sgx * 8;
    u16* const As_w = &As[(w * 8) * 64];
    u16* const Bs_w = &Bs[(w * 8) * 64];

#pragma unroll 4
    for (int k0 = 0; k0 < KC; k0 += 64) {
        __syncthreads();
#pragma unroll
        for (int j = 0; j < 4; j++)
            gload_lds16(Ag + (size_t)(j * 32) * KC + k0, As_w + j * 32 * 64);
#pragma unroll
        for (int j = 0; j < 2; j++)
            gload_lds16(Bg + (size_t)(j * 32) * KC + k0, Bs_w + j * 32 * 64);
        __syncthreads();
#pragma unroll
        for (int ks4 = 0; ks4 < 2; ks4++) {
            bf16x8 af[2], bfr[4];
#pragma unroll
            for (int i = 0; i < 2; i++)
                af[i] = ldfrag(&As[(wm + i * 16 + ml) * 64 +
                                   (((ks4 * 4 + quad) ^ (ml & 7)) * 8)]);
#pragma unroll
            for (int i = 0; i < 4; i++)
                bfr[i] = ldfrag(&Bs[(i * 16 + ml) * 64 +
                                    (((ks4 * 4 + quad) ^ (ml & 7)) * 8)]);
#pragma unroll
            for (int mt = 0; mt < 2; mt++)
#pragma unroll
                for (int nt = 0; nt < 4; nt++)
                    acc[mt][nt] = __builtin_amdgcn_mfma_f32_16x16x32_bf16(
                        bfr[nt], af[mt], acc[mt][nt], 0, 0, 0);
        }
    }
    // swapped layout: m = m0+wm+mt*16+ml, n = n0+nt*16+quad*4+rg -> float4 + Res
#pragma unroll
    for (int mt = 0; mt < 2; mt++) {
        const int m = m0 + wm + mt * 16 + ml;
#pragma unroll
        for (int nt = 0; nt < 4; nt++) {
            const int nb = n0 + nt * 16 + quad * 4;
            float4 r = *(const float4*)&Res[(size_t)m * Nst + nb];
            float4 o;
            o.x = acc[mt][nt][0] + r.x;
            o.y = acc[mt][nt][1] + r.y;
            o.z = acc[mt][nt][2] + r.z;
            o.w = acc[mt][nt][3] + r.w;
            *(float4*)&C[(size_t)m * Nst + nb] = o;
        }
    }
}

// ---------------- depthwise causal conv(4) + bias + SiLU, 4-t x 8-ch per thread ----------------
#define NGRAN (CONVDIM / 8)   // 288 granules of 8 channels per row
__global__ __launch_bounds__(256) void conv_silu_kernel(
    const u16* __restrict__ zx, const u16* __restrict__ cwT,
    const float* __restrict__ cb, const float* __restrict__ dt_bias,
    u16* __restrict__ out, float* __restrict__ dts)
{
    int idx = blockIdx.x * 256 + threadIdx.x;   // over (NROWS/4)*NGRAN = 294912
    if (idx < B_SZ * NHEADS * T_SZ) {           // fused softplus(dt)
        int t = idx & (T_SZ - 1);
        int bh = idx >> 11;
        int h = bh & 31, b = bh >> 5;
        float v = bf2f(zx[(size_t)(b * T_SZ + t) * DINPROJ + (DINNER + CONVDIM) + h]) + dt_bias[h];
        float sp = (v > 20.f) ? v : log1pf(expf(v));
        dts[((size_t)bh << 11) + t] = sp;
    }
    int gr = idx % NGRAN;
    int q  = idx / NGRAN;            // [0, NROWS/4)
    int bt0 = q * 4;
    int t0 = bt0 & (T_SZ - 1);
    int c0 = gr * 8;
    const u16* base = zx + (size_t)bt0 * DINPROJ + DINNER + c0;
    u16x8 xr[7];
#pragma unroll
    for (int i = 0; i < 7; i++) {
        int tt = t0 + i - 3;
        if (tt < 0) xr[i] = u16x8{};
        else xr[i] = *(const u16x8*)(base + (ptrdiff_t)(i - 3) * DINPROJ);
    }
    u16x8 wv[4];
#pragma unroll
    for (int k = 0; k < 4; k++) wv[k] = *(const u16x8*)&cwT[k * CONVDIM + c0];
    float bias[8];
#pragma unroll
    for (int u = 0; u < 8; u++) bias[u] = cb[c0 + u];
#pragma unroll
    for (int u4 = 0; u4 < 4; u4++) {
        float acc[8];
#pragma unroll
        for (int u = 0; u < 8; u++) acc[u] = bias[u];
#pragma unroll
        for (int k = 0; k < 4; k++) {
            u16x8 xv = xr[u4 + k];
#pragma unroll
            for (int u = 0; u < 8; u++)
                acc[u] += bf2f(xv[u]) * bf2f(wv[k][u]);
        }
        u16 res[8];
#pragma unroll
        for (int u = 0; u < 8; u++) {
            float s = acc[u] / (1.f + expf(-acc[u]));
            res[u] = f2bf(s);
        }
        *(u16x8*)&out[(size_t)(bt0 + u4) * CONVDIM + c0] = *(u16x8*)res;
    }
}

// ---------------- K1: per-chunk cumsum (shfl-scan) + chunk-local state S = Xw^T @ B ------------
// T14 reorder: all 12 X/B global loads issued BEFORE the scan; BsT written
// immediately; X regs held across scan (HBM latency hides under scan barriers).
__global__ __launch_bounds__(256) void chunk_state_kernel(
    const u16* __restrict__ xbc, const float* __restrict__ dts_g,
    const float* __restrict__ A_log, float* __restrict__ cs_g, u16* __restrict__ S_bf)
{
    const int g = blockIdx.x;
    const int b = g >> 9, rem = g & 511, c = rem >> 5, h = rem & 31;
    const int tid = threadIdx.x;
    __shared__ float tmp[128], dt_l[128], d2e[128];
    __shared__ float wtot;
    __shared__ u16 Xw[64][136];
    __shared__ u16 BsT[128][136];
    const float A = -__expf(A_log[h]);
    const size_t rowbase = ((size_t)(b * T_SZ + c * L_CH)) * CONVDIM;
    // issue dt load first (scan critical path), then all X/B loads
    float dval = 0.f;
    if (tid < 128)
        dval = dts_g[(((size_t)(b * 32 + h)) << 11) + (c << 7) + tid];
    u16x8 xvr[4];
#pragma unroll
    for (int r = 0; r < 4; r++) {
        int vv = tid + r * 256;
        int t = vv >> 3, p0 = (vv & 7) << 3;
        xvr[r] = *(const u16x8*)&xbc[rowbase + (size_t)t * CONVDIM + h * 64 + p0];
    }
    // B rows: load + write LDS immediately (independent of scan)
#pragma unroll
    for (int r = 0; r < 8; r++) {
        int vv = tid + r * 256;
        int t = vv >> 4, n0 = (vv & 15) << 3;
        u16x8 bv = *(const u16x8*)&xbc[rowbase + (size_t)t * CONVDIM + DINNER + n0];
        const int tc = (t & 7) | (((t >> 3) ^ ((n0 >> 3) & 15)) << 3);
#pragma unroll
        for (int u = 0; u < 8; u++) BsT[n0 + u][tc] = bv[u];
    }
    // scan (2 barriers) overlaps the outstanding memory traffic
    float v = 0.f;
    if (tid < 128) {
        dt_l[tid] = dval;
        v = dval * A;
#pragma unroll
        for (int off = 1; off < 64; off <<= 1) {
            float pv = __shfl_up(v, off, 64);
            if ((tid & 63) >= off) v += pv;
        }
        if (tid == 63) wtot = v;
    }
    __syncthreads();
    if (tid < 128) {
        if (tid >= 64) v += wtot;
        tmp[tid] = v;
        cs_g[(((size_t)(b * 32 + h)) << 11) + (c << 7) + tid] = v;
    }
    __syncthreads();
    if (tid < 128) {
        d2e[tid] = __expf(tmp[127] - v) * dt_l[tid];
    }
    __syncthreads();
#pragma unroll
    for (int r = 0; r < 4; r++) {
        int vv = tid + r * 256;
        int t = vv >> 3, p0 = (vv & 7) << 3;
        float s = d2e[t];
        const int tc = (t & 7) | (((t >> 3) ^ ((p0 >> 3) & 15)) << 3);
#pragma unroll
        for (int u = 0; u < 8; u++) Xw[p0 + u][tc] = f2bf(bf2f(xvr[r][u]) * s);
    }
    __syncthreads();
    const int lane = tid & 63, wv = tid >> 6, ml = lane & 15, quad = lane >> 4;
    f32x4 acc[8] = {};
    const int arow = wv * 16 + ml;
    const int asw = (arow >> 3) & 15;
    for (int k0 = 0; k0 < 128; k0 += 32) {
        bf16x8 af = ldfrag(&Xw[arow][(((k0 >> 3) + quad) ^ asw) << 3]);
#pragma unroll
        for (int nt = 0; nt < 8; nt++) {
            const int brow = nt * 16 + ml;
            bf16x8 bf = ldfrag(&BsT[brow][(((k0 >> 3) + quad) ^ ((brow >> 3) & 15)) << 3]);
            acc[nt] = __builtin_amdgcn_mfma_f32_16x16x32_bf16(bf, af, acc[nt], 0, 0, 0);
        }
    }
    // swapped layout: p = wv*16+ml, n = nt*16+quad*4+rg -> u16x4 stores
    const size_t base = (size_t)g * 8192;
    const int p = wv * 16 + ml;
#pragma unroll
    for (int nt = 0; nt < 8; nt++) {
        const int nb = nt * 16 + quad * 4;
        u16x4 pk;
#pragma unroll
        for (int rg = 0; rg < 4; rg++) pk[rg] = f2bf(acc[nt][rg]);
        *(u16x4*)&S_bf[base + p * 128 + nb] = pk;
    }
}

// ---------------- K2: inter-chunk recurrence, in-place, element-parallel, load-pipelined --------
__global__ __launch_bounds__(256) void state_pass_kernel(
    const float* __restrict__ cs_g, u16* __restrict__ S_bf)
{
    const int bh = blockIdx.x >> 3, b = bh >> 5, h = bh & 31;
    const int off = (blockIdx.x & 7) * 1024 + threadIdx.x * 4;
    const float* csb = cs_g + (((size_t)(b * 32 + h)) << 11);
    float H[4] = {0.f, 0.f, 0.f, 0.f};
    const size_t step = (size_t)32 * 8192;
    size_t slot = ((size_t)(b * NCH * 32 + h)) * 8192 + off;
    u16x4 tv = *(const u16x4*)&S_bf[slot];
    for (int c = 0; c < NCH; c++) {
        u16x4 tvn = tv;
        if (c + 1 < NCH) tvn = *(const u16x4*)&S_bf[slot + step];   // prefetch next
        float decay = __expf(csb[(c << 7) + 127]);
        u16x4 hw;
#pragma unroll
        for (int i = 0; i < 4; i++) hw[i] = f2bf(H[i]);
        *(u16x4*)&S_bf[slot] = hw;                                   // store prev-state
#pragma unroll
        for (int i = 0; i < 4; i++) H[i] = H[i] * decay + bf2f(tv[i]);
        tv = tvn; slot += step;
    }
}

// ---------------- K3: chunk output -- LDS-staged B/H + swapped D[p][t] accumulators ------------
__global__ __launch_bounds__(256) void chunk_out_kernel(
    const u16* __restrict__ xbc, const float* __restrict__ dts_g,
    const float* __restrict__ cs_g, const u16* __restrict__ H_bf,
    const float* __restrict__ Dv, u16* __restrict__ yraw)
{
    const int g = blockIdx.x;
    const int b = g >> 9, rem = g & 511, c = rem >> 5, h = rem & 31;
    const int tid = threadIdx.x;
    __shared__ u16 Xs[64][136];     // X^T [p][t], granule-XOR swizzled
    __shared__ u16 Gs[128][40];     // masked P tile
    __shared__ u16 Hs[64 * 128];    // H [p][n], row-granule swizzled
    __shared__ u16 Bsh[128 * 128];  // B [j][n], row-granule swizzled
    __shared__ float cs_l[128], P_l[128], dt_l[128];
    const size_t rowbase = ((size_t)(b * T_SZ + c * L_CH)) * CONVDIM;
    const u16* Cg = xbc + rowbase + DINNER + 128;
    const u16* Bg = xbc + rowbase + DINNER;
    const u16* Hg = H_bf + (size_t)g * 8192;
    // async coalesced staging of H (16KB) and B (32KB); granule pre-swizzle on source
#pragma unroll
    for (int r = 0; r < 4; r++) {
        int i = r * 256 + tid;
        int row = i >> 4, slot = i & 15;
        gload_lds16(Hg + row * 128 + ((slot ^ (row & 15)) << 3), &Hs[i * 8]);
    }
#pragma unroll
    for (int r = 0; r < 8; r++) {
        int i = r * 256 + tid;
        int row = i >> 4, slot = i & 15;
        gload_lds16(Bg + (size_t)row * CONVDIM + ((slot ^ (row & 15)) << 3), &Bsh[i * 8]);
    }
    if (tid < 128) {
        float cs = cs_g[(((size_t)(b * 32 + h)) << 11) + (c << 7) + tid];
        cs_l[tid] = cs; P_l[tid] = __expf(cs);
        dt_l[tid] = dts_g[(((size_t)(b * 32 + h)) << 11) + (c << 7) + tid];
    }
#pragma unroll
    for (int r = 0; r < 4; r++) {
        int v = tid + r * 256; int t = v >> 3, p0 = (v & 7) << 3;
        u16x8 xv = *(const u16x8*)&xbc[rowbase + (size_t)t * CONVDIM + h * 64 + p0];
        const int tc = (t & 7) | (((t >> 3) ^ ((p0 >> 3) & 15)) << 3);
#pragma unroll
        for (int u = 0; u < 8; u++) Xs[p0 + u][tc] = xv[u];
    }
    __syncthreads();
    const int lane = tid & 63, wv = tid >> 6, ml = lane & 15, quad = lane >> 4;
    const int trow = wv * 32;
    // HOIST: C fragments (t-rows of this wave), 2nd operand everywhere.
    bf16x8 cf[2][4];
#pragma unroll
    for (int mt = 0; mt < 2; mt++)
#pragma unroll
        for (int kk = 0; kk < 4; kk++)
            cf[mt][kk] = ldfrag(Cg + (size_t)(trow + mt * 16 + ml) * CONVDIM + kk * 32 + quad * 8);
    // Y = C.H^T, swapped: accY[mt][pt] = D[p][t], p = pt*16+quad*4+rg, t = trow+mt*16+ml
    f32x4 accY[2][4] = {};
#pragma unroll
    for (int kk = 0; kk < 4; kk++) {
        const int sw = (((kk << 2) + quad) ^ ml) << 3;   // row&15 == ml
#pragma unroll
        for (int pt = 0; pt < 4; pt++) {
            bf16x8 bf = ldfrag(&Hs[(pt * 16 + ml) * 128 + sw]);
            accY[0][pt] = __builtin_amdgcn_mfma_f32_16x16x32_bf16(bf, cf[0][kk], accY[0][pt], 0, 0, 0);
            accY[1][pt] = __builtin_amdgcn_mfma_f32_16x16x32_bf16(bf, cf[1][kk], accY[1][pt], 0, 0, 0);
        }
    }
#pragma unroll
    for (int mt = 0; mt < 2; mt++) {
        const float pp = P_l[trow + mt * 16 + ml];
#pragma unroll
        for (int pt = 0; pt < 4; pt++)
#pragma unroll
            for (int rg = 0; rg < 4; rg++) accY[mt][pt][rg] *= pp;
    }
    for (int js = 0; js < 4; js++) {
        const int j0 = js * 32;
        // Ga[mt][jt] = D[j][t]: j = j0+jt*16+quad*4+rg, t = trow+mt*16+ml
        f32x4 Ga[2][2] = {};
#pragma unroll
        for (int kk = 0; kk < 4; kk++) {
            const int sw = (((kk << 2) + quad) ^ ml) << 3;   // row&15 == ml
            bf16x8 bf0 = ldfrag(&Bsh[(j0 + ml) * 128 + sw]);
            bf16x8 bf1 = ldfrag(&Bsh[(j0 + 16 + ml) * 128 + sw]);
            Ga[0][0] = __builtin_amdgcn_mfma_f32_16x16x32_bf16(bf0, cf[0][kk], Ga[0][0], 0, 0, 0);
            Ga[0][1] = __builtin_amdgcn_mfma_f32_16x16x32_bf16(bf1, cf[0][kk], Ga[0][1], 0, 0, 0);
            Ga[1][0] = __builtin_amdgcn_mfma_f32_16x16x32_bf16(bf0, cf[1][kk], Ga[1][0], 0, 0, 0);
            Ga[1][1] = __builtin_amdgcn_mfma_f32_16x16x32_bf16(bf1, cf[1][kk], Ga[1][1], 0, 0, 0);
        }
        // causal mask * decay -> Gs (u16x4 writes: 4 consecutive j at fixed t)
#pragma unroll
        for (int mt = 0; mt < 2; mt++) {
            const int t = trow + mt * 16 + ml;
            const float cst = cs_l[t];
#pragma unroll
            for (int jt = 0; jt < 2; jt++) {
                u16x4 pk;
#pragma unroll
                for (int rg = 0; rg < 4; rg++) {
                    int j = j0 + jt * 16 + quad * 4 + rg;
                    float val = 0.f;
                    if (t >= j) val = Ga[mt][jt][rg] * __expf(cst - cs_l[j]) * dt_l[j];
                    pk[rg] = f2bf(val);
                }
                *(u16x4*)&Gs[t][jt * 16 + quad * 4] = pk;
            }
        }
#pragma unroll
        for (int mt = 0; mt < 2; mt++) {
            bf16x8 ag = ldfrag(&Gs[trow + mt * 16 + ml][quad * 8]);
#pragma unroll
            for (int pt = 0; pt < 4; pt++) {
                const int xrow = pt * 16 + ml;
                bf16x8 bx = ldfrag(&Xs[xrow][(((j0 >> 3) + quad) ^ ((xrow >> 3) & 15)) << 3]);
                accY[mt][pt] = __builtin_amdgcn_mfma_f32_16x16x32_bf16(bx, ag, accY[mt][pt], 0, 0, 0);
            }
        }
    }
    const float Dh = Dv[h];
    const size_t ybase = ((size_t)(b * T_SZ + c * L_CH)) * DINNER;
#pragma unroll
    for (int mt = 0; mt < 2; mt++) {
        const int t = trow + mt * 16 + ml;
#pragma unroll
        for (int pt = 0; pt < 4; pt++) {
            const int pb = pt * 16 + quad * 4;
            const int tc = (t & 7) | (((t >> 3) ^ ((pb >> 3) & 15)) << 3);
            u16x4 pk;
#pragma unroll
            for (int rg = 0; rg < 4; rg++)
                pk[rg] = f2bf(accY[mt][pt][rg] + Dh * bf2f(Xs[pb + rg][tc]));
            *(u16x4*)&yraw[ybase + (size_t)t * DINNER + h * 64 + pb] = pk;
        }
    }
}

// ---------------- y = rmsnorm(yraw * silu(z)) * gnorm_w (D=2048), vectorized ----------------
__global__ __launch_bounds__(256) void postnorm_kernel(
    const u16* __restrict__ yraw, const u16* __restrict__ zx,
    const float* __restrict__ gw, u16* __restrict__ out)
{
    const int row = blockIdx.x;
    const int tid = threadIdx.x;
    u16x8 yv = *(const u16x8*)(yraw + (size_t)row * DINNER + tid * 8);
    u16x8 zv = *(const u16x8*)(zx + (size_t)row * DINPROJ + tid * 8);
    float vals[8]; float ss = 0.f;
#pragma unroll
    for (int i = 0; i < 8; i++) {
        float y = bf2f(yv[i]);
        float z = bf2f(zv[i]);
        float s = z / (1.f + expf(-z));
        float t = y * s; vals[i] = t; ss += t * t;
    }
#pragma unroll
    for (int o = 32; o; o >>= 1) ss += __shfl_xor(ss, o);
    __shared__ float red[4];
    if ((tid & 63) == 0) red[tid >> 6] = ss;
    __syncthreads();
    ss = red[0] + red[1] + red[2] + red[3];
    float sc = rsqrtf(ss / (float)DINNER + 1e-5f);
    u16 o8[8];
#pragma unroll
    for (int i = 0; i < 8; i++) o8[i] = f2bf(vals[i] * sc * gw[tid * 8 + i]);
    *(u16x8*)(out + (size_t)row * DINNER + tid * 8) = *(u16x8*)o8;
}

extern "C" void kernel_launch(void* const* d_in, const int* in_sizes, int n_in,
                              void* d_out, int out_size, void* d_ws, size_t ws_size,
                              hipStream_t stream) {
    const float* x       = (const float*)d_in[0];
    const float* W_in    = (const float*)d_in[1];
    const float* conv_w  = (const float*)d_in[2];
    const float* conv_b  = (const float*)d_in[3];
    const float* dt_bias = (const float*)d_in[4];
    const float* A_log   = (const float*)d_in[5];
    const float* Dv      = (const float*)d_in[6];
    const float* norm_w  = (const float*)d_in[7];
    const float* gnorm_w = (const float*)d_in[8];
    const float* W_out   = (const float*)d_in[9];
    float* out = (float*)d_out;

    char* ws = (char*)d_ws;
    u16*   xn    = (u16*)(ws);                  // [0, 8.39M)  (aliases S_bf later)
    u16*   W_inT = (u16*)(ws + 8388608);        // [4480][1024] bf16 (dead after GEMM1)
    u16*   S_bf  = (u16*)(ws);                  // 16.78M, from chunk_state on
    float* cs_g  = (float*)(ws + 16777216);
    u16*   zx    = (u16*)(ws + 17563648);       // 35,913,728 B
    u16*   xbc   = (u16*)(ws + 53477376);       // 18,874,368 B
    float* dts   = (float*)(ws + 72351744);     //    524,288 B
    u16*   yraw  = (u16*)(ws + 72876032);       // 16,777,216 B
    u16*   cwT   = (u16*)(ws + 89653248);       //     18,432 B
    u16*   W_outT= (u16*)(ws + 89671680);       //  4,194,304 B (end 93,865,984)
    u16*   ynorm = yraw;                        // postnorm in-place safe

    prep_kernel<<<5729, 256, 0, stream>>>(
        W_in, W_inT, W_out, W_outT, x, norm_w, xn, conv_w, cwT);
    // GEMM1: r8-exact single 1120-block launch (r7 XCD-region swizzle, scalar epilogue)
    gemm128_kernel<DMODEL><<<1120, 256, 0, stream>>>(
        xn, W_inT, zx, DINPROJ);
    conv_silu_kernel<<<(NROWS / 4 * NGRAN) / 256, 256, 0, stream>>>(
        zx, cwT, conv_b, dt_bias, xbc, dts);
    chunk_state_kernel<<<B_SZ * NCH * NHEADS, 256, 0, stream>>>(xbc, dts, A_log, cs_g, S_bf);
    state_pass_kernel<<<B_SZ * NHEADS * 8, 256, 0, stream>>>(cs_g, S_bf);
    chunk_out_kernel<<<B_SZ * NCH * NHEADS, 256, 0, stream>>>(xbc, dts, cs_g, S_bf, Dv, yraw);
    postnorm_kernel<<<NROWS, 256, 0, stream>>>(yraw, zx, gnorm_w, ynorm);
    // GEMM2: 128x64, 1D grid 512 with XCD-region mapping (64 blocks/XCD, n-fast)
    gemm128x64_kernel<DINNER><<<512, 256, 0, stream>>>(
        ynorm, W_outT, out, x, DMODEL);
}